// Round 1
// baseline (757.175 us; speedup 1.0000x reference)
//
#include <hip/hip_runtime.h>
#include <stdint.h>

typedef short bf16x8 __attribute__((ext_vector_type(8)));
typedef float f32x4 __attribute__((ext_vector_type(4)));

#define BATCH 8192
#define EMBED 8192
#define U0    1024
#define U1    256
#define NHEAD 6

// ---------- helpers ----------
__device__ __forceinline__ unsigned short f2bf(float f) {
  union { float f; unsigned int u; } v; v.f = f;
  unsigned int u = v.u;
  unsigned int r = u + 0x7FFFu + ((u >> 16) & 1u);  // RNE
  return (unsigned short)(r >> 16);
}
__device__ __forceinline__ unsigned int pk2(float lo, float hi) {
  return (unsigned int)f2bf(lo) | ((unsigned int)f2bf(hi) << 16);
}
__device__ __forceinline__ void async_copy16(const void* g, void* l) {
  __builtin_amdgcn_global_load_lds((const __attribute__((address_space(1))) void*)g,
                                   (__attribute__((address_space(3))) void*)l, 16, 0, 0);
}

// ---------- kernel 1: x fp32 -> bf16 (row-major, K contiguous) ----------
__global__ void cvt_x_kernel(const float* __restrict__ x, unsigned short* __restrict__ xb) {
  long i = ((long)blockIdx.x * 256 + threadIdx.x) * 8;
  float4 a = *(const float4*)(x + i);
  float4 b = *(const float4*)(x + i + 4);
  uint4 r;
  r.x = pk2(a.x, a.y); r.y = pk2(a.z, a.w);
  r.z = pk2(b.x, b.y); r.w = pk2(b.z, b.w);
  *(uint4*)(xb + i) = r;
}

// ---------- kernel 2: transpose + convert: in[R][C] fp32 -> out[C][R] bf16 ----------
// R, C multiples of 64. blockIdx.z selects a slab (for W1 heads).
__global__ void transpose_cvt_kernel(const float* __restrict__ in, unsigned short* __restrict__ out,
                                     int R, int C, long in_z, long out_z) {
  __shared__ unsigned short tile[64][65];
  const float* inp = in + (long)blockIdx.z * in_z;
  unsigned short* outp = out + (long)blockIdx.z * out_z;
  int r0 = blockIdx.x * 64;
  int c0 = blockIdx.y * 64;
  int lc = threadIdx.x & 63;
  int lr = threadIdx.x >> 6;  // 0..3
#pragma unroll
  for (int i = 0; i < 16; i++) {
    int r = lr + i * 4;
    tile[r][lc] = f2bf(inp[(long)(r0 + r) * C + (c0 + lc)]);
  }
  __syncthreads();
#pragma unroll
  for (int i = 0; i < 16; i++) {
    int c = lr + i * 4;
    outp[(long)(c0 + c) * R + (r0 + lc)] = tile[lc][c];
  }
}

// ---------- kernel 3: bucket rows by command (single block) ----------
__global__ void bucket_kernel(const int* __restrict__ cmd, int* __restrict__ idxlist,
                              int* __restrict__ meta) {
  __shared__ int cnt[NHEAD], cur[NHEAD], off[NHEAD + 1];
  int tid = threadIdx.x;
  if (tid < NHEAD) cnt[tid] = 0;
  __syncthreads();
  for (int b = tid; b < BATCH; b += blockDim.x) atomicAdd(&cnt[cmd[b]], 1);
  __syncthreads();
  if (tid == 0) {
    int s = 0;
    for (int h2 = 0; h2 < NHEAD; h2++) { off[h2] = s; s += cnt[h2]; }
    off[NHEAD] = s;
  }
  __syncthreads();
  if (tid < NHEAD) cur[tid] = off[tid];
  if (tid <= NHEAD) meta[tid] = off[tid];
  __syncthreads();
  for (int b = tid; b < BATCH; b += blockDim.x) {
    int p = atomicAdd(&cur[cmd[b]], 1);
    idxlist[p] = b;
  }
}

// ---------- kernel 4: GEMM  h = relu(x @ fc_W + fc_b), bf16 MFMA ----------
// A = xb[8192][8192] bf16 (M x K); B = wt[1024][8192] bf16 (N x K, i.e. fc_W^T).
// 128x128 tile, BK=64, 4 waves in 2x2, each wave 64x64 (4x4 of 16x16x32 MFMA).
// LDS holds tiles in fragment order: slot((wm*2+ks)*4+mi)*64+lane, 16B each.
__global__ __launch_bounds__(256) void gemm_kernel(const unsigned short* __restrict__ xb,
                                                   const unsigned short* __restrict__ wt,
                                                   const float* __restrict__ fc_b,
                                                   unsigned short* __restrict__ h) {
  __shared__ uint4 As[1024];  // 16 KB
  __shared__ uint4 Bs[1024];  // 16 KB
  int tid  = threadIdx.x;
  int lane = tid & 63;
  int wave = tid >> 6;
  int wm = wave >> 1, wn = wave & 1;
  int m0 = blockIdx.y * 128;
  int n0 = blockIdx.x * 128;
  int l15 = lane & 15, lq = lane >> 4;

  // staging sources: combo c = (cwm*2+cks)*4+cmi ; this wave handles c = wave*4..wave*4+3
  long asrc[4], bsrc[4];
#pragma unroll
  for (int j = 0; j < 4; j++) {
    int c = wave * 4 + j;
    int cwm = c >> 3, cks = (c >> 2) & 1, cmi = c & 3;
    int kofs = cks * 32 + lq * 8;
    asrc[j] = (long)(m0 + cwm * 64 + cmi * 16 + l15) * EMBED + kofs;
    bsrc[j] = (long)(n0 + cwm * 64 + cmi * 16 + l15) * EMBED + kofs;
  }

  f32x4 zero = {0.f, 0.f, 0.f, 0.f};
  f32x4 acc[4][4];
#pragma unroll
  for (int mi = 0; mi < 4; mi++)
#pragma unroll
    for (int ni = 0; ni < 4; ni++) acc[mi][ni] = zero;

  for (int k0 = 0; k0 < EMBED; k0 += 64) {
    __syncthreads();
#pragma unroll
    for (int j = 0; j < 4; j++) {
      int c = wave * 4 + j;
      async_copy16(xb + asrc[j] + k0, &As[c * 64 + lane]);
      async_copy16(wt + bsrc[j] + k0, &Bs[c * 64 + lane]);
    }
    __syncthreads();
#pragma unroll
    for (int ks = 0; ks < 2; ks++) {
      bf16x8 af[4], bfr[4];
#pragma unroll
      for (int mi = 0; mi < 4; mi++) af[mi] = *(const bf16x8*)&As[((wm * 2 + ks) * 4 + mi) * 64 + lane];
#pragma unroll
      for (int ni = 0; ni < 4; ni++) bfr[ni] = *(const bf16x8*)&Bs[((wn * 2 + ks) * 4 + ni) * 64 + lane];
#pragma unroll
      for (int mi = 0; mi < 4; mi++)
#pragma unroll
        for (int ni = 0; ni < 4; ni++)
          acc[mi][ni] = __builtin_amdgcn_mfma_f32_16x16x32_bf16(af[mi], bfr[ni], acc[mi][ni], 0, 0, 0);
    }
  }

  // epilogue: +bias, relu, store bf16.  D: col=lane&15, row=(lane>>4)*4+reg
#pragma unroll
  for (int ni = 0; ni < 4; ni++) {
    int col = n0 + wn * 64 + ni * 16 + l15;
    float bias = fc_b[col];
#pragma unroll
    for (int mi = 0; mi < 4; mi++) {
      int rbase = m0 + wm * 64 + mi * 16 + lq * 4;
#pragma unroll
      for (int r = 0; r < 4; r++) {
        float v = acc[mi][ni][r] + bias;
        v = v > 0.f ? v : 0.f;
        h[(long)(rbase + r) * U0 + col] = f2bf(v);
      }
    }
  }
}

// ---------- kernel 5: selected-head MLP + epilogue ----------
// grid (256, 6): y = head, x = 32-row tile of that head's bucket. 4 waves over N=256.
__global__ __launch_bounds__(256) void head_kernel(const unsigned short* __restrict__ h,
                                                   const unsigned short* __restrict__ w1t,
                                                   const float* __restrict__ W1,
                                                   const float* __restrict__ b1,
                                                   const float* __restrict__ W2,
                                                   const float* __restrict__ b2,
                                                   const float* __restrict__ ego,
                                                   const int* __restrict__ idxlist,
                                                   const int* __restrict__ meta,
                                                   float* __restrict__ out) {
  int hd = blockIdx.y;
  int off = meta[hd];
  int cnt = meta[hd + 1] - off;
  int t0 = blockIdx.x * 32;
  if (t0 >= cnt) return;

  __shared__ int ridx[32];
  __shared__ float h1s[32][257];
  int tid = threadIdx.x;
  if (tid < 32) {
    int i = t0 + tid;
    ridx[tid] = idxlist[off + (i < cnt ? i : 0)];
  }
  __syncthreads();

  int lane = tid & 63, wave = tid >> 6;
  int l15 = lane & 15, lq = lane >> 4;

  long abase[2];
#pragma unroll
  for (int mi = 0; mi < 2; mi++) abase[mi] = (long)ridx[mi * 16 + l15] * U0 + lq * 8;
  long bbase[4];
#pragma unroll
  for (int ni = 0; ni < 4; ni++)
    bbase[ni] = (long)(hd * 256 + wave * 64 + ni * 16 + l15) * 1024 + lq * 8;

  f32x4 zero = {0.f, 0.f, 0.f, 0.f};
  f32x4 acc[2][4];
#pragma unroll
  for (int mi = 0; mi < 2; mi++)
#pragma unroll
    for (int ni = 0; ni < 4; ni++) acc[mi][ni] = zero;

#pragma unroll 2
  for (int k0 = 0; k0 < 1024; k0 += 32) {
    bf16x8 af[2], bfr[4];
#pragma unroll
    for (int mi = 0; mi < 2; mi++) af[mi] = *(const bf16x8*)(h + abase[mi] + k0);
#pragma unroll
    for (int ni = 0; ni < 4; ni++) bfr[ni] = *(const bf16x8*)(w1t + bbase[ni] + k0);
#pragma unroll
    for (int mi = 0; mi < 2; mi++)
#pragma unroll
      for (int ni = 0; ni < 4; ni++)
        acc[mi][ni] = __builtin_amdgcn_mfma_f32_16x16x32_bf16(af[mi], bfr[ni], acc[mi][ni], 0, 0, 0);
  }

  // ego contribution (fp32 exact) + bias + relu -> LDS
  const float* W1e = W1 + (long)hd * 1027 * 256 + (long)1024 * 256;  // rows 1024..1026
#pragma unroll
  for (int mi = 0; mi < 2; mi++)
#pragma unroll
    for (int r = 0; r < 4; r++) {
      int rl = mi * 16 + lq * 4 + r;
      int b = ridx[rl];
      float e0 = ego[b * 3 + 0], e1 = ego[b * 3 + 1], e2 = ego[b * 3 + 2];
#pragma unroll
      for (int ni = 0; ni < 4; ni++) {
        int col = wave * 64 + ni * 16 + l15;
        float v = acc[mi][ni][r] + b1[hd * 256 + col]
                + e0 * W1e[col] + e1 * W1e[256 + col] + e2 * W1e[512 + col];
        h1s[rl][col] = v > 0.f ? v : 0.f;
      }
    }
  __syncthreads();

  // h2 = h1 @ W2[hd] + b2[hd]; tanh/softplus epilogue; scatter by original row
  if (tid < 128) {
    int t = tid >> 2, o2 = tid & 3;
    if (t0 + t < cnt) {
      const float* w2 = W2 + (long)hd * 256 * 4;
      float sum = b2[hd * 4 + o2];
      for (int i = 0; i < 256; i++) sum += h1s[t][i] * w2[i * 4 + o2];
      int b = ridx[t];
      float res;
      if (o2 < 2) {
        res = 5.0f * tanhf(sum * 0.2f);
      } else {
        float z = sum + 4.99323838f;  // log(exp(5)-1)
        res = (z > 20.f ? z : log1pf(expf(z))) + 1e-4f;
      }
      out[b * 4 + o2] = res;
    }
  }
}

// ---------- launcher ----------
extern "C" void kernel_launch(void* const* d_in, const int* in_sizes, int n_in,
                              void* d_out, int out_size, void* d_ws, size_t ws_size,
                              hipStream_t stream) {
  const float* x   = (const float*)d_in[0];
  const int*   cmd = (const int*)d_in[1];
  const float* ego = (const float*)d_in[2];
  const float* fcW = (const float*)d_in[3];
  const float* fcb = (const float*)d_in[4];
  const float* W1  = (const float*)d_in[5];
  const float* b1  = (const float*)d_in[6];
  const float* W2  = (const float*)d_in[7];
  const float* b2  = (const float*)d_in[8];
  float* out = (float*)d_out;

  char* ws = (char*)d_ws;
  unsigned short* xb   = (unsigned short*)(ws);                 // 128 MB
  unsigned short* wt   = (unsigned short*)(ws + 134217728);     // 16 MB
  unsigned short* hbuf = (unsigned short*)(ws + 150994944);     // 16 MB
  unsigned short* w1t  = (unsigned short*)(ws + 167772160);     // 3 MB
  int* idxlist         = (int*)(ws + 170917888);                // 32 KB
  int* meta            = (int*)(ws + 170950656);                // 7 ints

  hipLaunchKernelGGL(cvt_x_kernel, dim3(32768), dim3(256), 0, stream, x, xb);
  hipLaunchKernelGGL(transpose_cvt_kernel, dim3(128, 16, 1), dim3(256), 0, stream,
                     fcW, wt, 8192, 1024, 0L, 0L);
  hipLaunchKernelGGL(transpose_cvt_kernel, dim3(16, 4, 6), dim3(256), 0, stream,
                     W1, w1t, 1024, 256, (long)1027 * 256, (long)256 * 1024);
  hipLaunchKernelGGL(bucket_kernel, dim3(1), dim3(1024), 0, stream, cmd, idxlist, meta);
  hipLaunchKernelGGL(gemm_kernel, dim3(8, 64), dim3(256), 0, stream, xb, wt, fcb, hbuf);
  hipLaunchKernelGGL(head_kernel, dim3(256, 6), dim3(256), 0, stream,
                     hbuf, w1t, W1, b1, W2, b2, ego, idxlist, meta, out);
}